// Round 1
// baseline (257.461 us; speedup 1.0000x reference)
//
#include <hip/hip_runtime.h>

typedef __attribute__((ext_vector_type(4))) short  short4v;
typedef __attribute__((ext_vector_type(4))) float  f32x4;
typedef __attribute__((ext_vector_type(4))) float  float4v;
typedef __attribute__((ext_vector_type(8))) unsigned short ushort8;
typedef __attribute__((ext_vector_type(4))) unsigned short ushort4v;

static constexpr int BB   = 2;
static constexpr int NN   = 2048;
static constexpr int DM   = 1024;
static constexpr int HH   = 16;
static constexpr int MTOT = BB * NN;   // 4096

__device__ __forceinline__ unsigned short f2bf(float f) {
    union { float f; unsigned int u; } v; v.f = f;
    unsigned int u = v.u;
    unsigned int r = (u + 0x7FFFu + ((u >> 16) & 1u)) >> 16;  // RNE
    return (unsigned short)r;
}
__device__ __forceinline__ float bf2f(unsigned short b) {
    union { unsigned int u; float f; } v; v.u = ((unsigned int)b) << 16;
    return v.f;
}

// ---------------------------------------------------------------------------
// Kernel 1: fp32 -> bf16 conversion for x, Wq, Wk, Wv, Wo (blockIdx.y selects)
// ---------------------------------------------------------------------------
__global__ __launch_bounds__(256) void convert_all(
    const float* __restrict__ x,  const float* __restrict__ wq,
    const float* __restrict__ wk, const float* __restrict__ wv,
    const float* __restrict__ wo,
    unsigned short* __restrict__ xb,  unsigned short* __restrict__ wqb,
    unsigned short* __restrict__ wkb, unsigned short* __restrict__ wvb,
    unsigned short* __restrict__ wob)
{
    const float* src; unsigned short* dst; int n;
    switch (blockIdx.y) {
        case 0: src = x;  dst = xb;  n = MTOT * DM; break;
        case 1: src = wq; dst = wqb; n = DM * DM;   break;
        case 2: src = wk; dst = wkb; n = DM * DM;   break;
        case 3: src = wv; dst = wvb; n = DM * DM;   break;
        default: src = wo; dst = wob; n = DM * DM;  break;
    }
    int nv = n >> 2;
    int stride = gridDim.x * blockDim.x;
    for (int i = blockIdx.x * blockDim.x + threadIdx.x; i < nv; i += stride) {
        float4v v = reinterpret_cast<const float4v*>(src)[i];
        ushort4v o;
        o[0] = f2bf(v[0]); o[1] = f2bf(v[1]); o[2] = f2bf(v[2]); o[3] = f2bf(v[3]);
        reinterpret_cast<ushort4v*>(dst)[i] = o;
    }
}

// ---------------------------------------------------------------------------
// Kernel 2: gate[b,h] = sigmoid(q[b,:] . Wqh[h,:] + bqh[h])   (tiny)
// ---------------------------------------------------------------------------
__global__ void gate_kernel(const float* __restrict__ q,
                            const float* __restrict__ Wqh,
                            const float* __restrict__ bqh,
                            float* __restrict__ gate)
{
    int t = threadIdx.x;
    if (t < BB * HH) {
        int b = t >> 4, h = t & 15;
        float s = bqh[h];
        for (int d = 0; d < 64; ++d) s += q[b * 64 + d] * Wqh[h * 64 + d];
        gate[t] = 1.f / (1.f + __expf(-s));
    }
}

// ---------------------------------------------------------------------------
// Kernel 3: GEMM  C[m,n] = sum_k A[m,k] * W[n,k] + bias[n]
//   A: (4096, 1024) bf16 row-major; W: (1024, 1024) bf16 row-major (B^T form)
//   blockIdx.z selects among up to 3 (W, bias, C) triples (fused QKV).
//   128x128 tile, BK=32, 4 waves (2x2), v_mfma_f32_16x16x16_bf16.
// ---------------------------------------------------------------------------
template <typename OUT>
__global__ __launch_bounds__(256) void gemm_bt(
    const unsigned short* __restrict__ A,
    const unsigned short* __restrict__ W0, const unsigned short* __restrict__ W1,
    const unsigned short* __restrict__ W2,
    const float* __restrict__ b0, const float* __restrict__ b1,
    const float* __restrict__ b2,
    OUT* __restrict__ C0, OUT* __restrict__ C1, OUT* __restrict__ C2)
{
    constexpr int BM = 128, BN = 128, BK = 32, LDT = 40; // LDT: padded, 80B (16B-aligned) stride
    constexpr int K = DM, Nd = DM;

    const unsigned short* W = (blockIdx.z == 0) ? W0 : (blockIdx.z == 1) ? W1 : W2;
    const float* bias        = (blockIdx.z == 0) ? b0 : (blockIdx.z == 1) ? b1 : b2;
    OUT* C                   = (blockIdx.z == 0) ? C0 : (blockIdx.z == 1) ? C1 : C2;

    __shared__ unsigned short As[BM * LDT];
    __shared__ unsigned short Ws[BN * LDT];

    const int tid  = threadIdx.x;
    const int lane = tid & 63;
    const int w    = tid >> 6;       // wave 0..3
    const int lr   = lane & 15;      // row-in-tile
    const int g    = lane >> 4;      // k-group 0..3
    const int wm   = w >> 1, wn = w & 1;
    const int bm   = blockIdx.y * BM, bn = blockIdx.x * BN;

    f32x4 acc[4][4] = {};

    for (int k0 = 0; k0 < K; k0 += BK) {
        __syncthreads();
        #pragma unroll
        for (int it = 0; it < 2; ++it) {
            int idx = it * 256 + tid;           // 0..511
            int row = idx >> 2, cv = idx & 3;   // 128 rows x 4 chunks of 8
            ushort8 va = *reinterpret_cast<const ushort8*>(&A[(size_t)(bm + row) * K + k0 + cv * 8]);
            *reinterpret_cast<ushort8*>(&As[row * LDT + cv * 8]) = va;
            ushort8 vw = *reinterpret_cast<const ushort8*>(&W[(size_t)(bn + row) * K + k0 + cv * 8]);
            *reinterpret_cast<ushort8*>(&Ws[row * LDT + cv * 8]) = vw;
        }
        __syncthreads();
        #pragma unroll
        for (int c = 0; c < 2; ++c) {          // two K=16 chunks
            short4v af[4], bf[4];
            #pragma unroll
            for (int mi = 0; mi < 4; ++mi)
                af[mi] = *reinterpret_cast<const short4v*>(&As[(wm * 64 + mi * 16 + lr) * LDT + c * 16 + g * 4]);
            #pragma unroll
            for (int ni = 0; ni < 4; ++ni)
                bf[ni] = *reinterpret_cast<const short4v*>(&Ws[(wn * 64 + ni * 16 + lr) * LDT + c * 16 + g * 4]);
            #pragma unroll
            for (int mi = 0; mi < 4; ++mi)
                #pragma unroll
                for (int ni = 0; ni < 4; ++ni)
                    acc[mi][ni] = __builtin_amdgcn_mfma_f32_16x16x16bf16_1k(af[mi], bf[ni], acc[mi][ni], 0, 0, 0);
        }
    }

    #pragma unroll
    for (int mi = 0; mi < 4; ++mi) {
        #pragma unroll
        for (int ni = 0; ni < 4; ++ni) {
            int colg = bn + wn * 64 + ni * 16 + lr;
            float bv = bias[colg];
            #pragma unroll
            for (int i = 0; i < 4; ++i) {
                int rowg = bm + wm * 64 + mi * 16 + 4 * g + i;
                float v = acc[mi][ni][i] + bv;
                if constexpr (sizeof(OUT) == 2) C[(size_t)rowg * Nd + colg] = (OUT)f2bf(v);
                else                            C[(size_t)rowg * Nd + colg] = (OUT)v;
            }
        }
    }
}

// ---------------------------------------------------------------------------
// Kernel 4: flash attention per (b, h), Q-tile = 64 rows, K-tile = 64.
//   Swapped QK^T: each wave computes T = K_tile (64xd) . Q_wave^T (dx16)
//   -> lane owns one q-row (lr), 16 kj values -> P stays in-register for PV.
//   V staged transposed in LDS for contiguous B-fragments.
//   Masked online softmax; gate folded into epilogue; out bf16 -> attb.
// ---------------------------------------------------------------------------
__global__ __launch_bounds__(256) void attn_kernel(
    const unsigned short* __restrict__ Qb, const unsigned short* __restrict__ Kb,
    const unsigned short* __restrict__ Vb, const int* __restrict__ mask,
    const float* __restrict__ gate, unsigned short* __restrict__ attb)
{
    constexpr int LDT = 72;  // padded stride (144B, 16B-aligned)
    __shared__ unsigned short Qs[64 * LDT];
    __shared__ unsigned short Ks[64 * LDT];
    __shared__ unsigned short Vts[64 * LDT];   // [dh][kj]
    __shared__ int maskS[64];

    const int tid  = threadIdx.x;
    const int lane = tid & 63;
    const int w    = tid >> 6;     // wave -> q-rows [w*16, w*16+16)
    const int lr   = lane & 15;
    const int g    = lane >> 4;
    const int b    = blockIdx.z, h = blockIdx.y;
    const int q0   = blockIdx.x * 64;

    // stage Q tile (64 x 64)
    #pragma unroll
    for (int it = 0; it < 2; ++it) {
        int idx = it * 256 + tid;
        int row = idx >> 3, cv = idx & 7;
        ushort8 v = *reinterpret_cast<const ushort8*>(&Qb[(size_t)(b * NN + q0 + row) * DM + h * 64 + cv * 8]);
        *reinterpret_cast<ushort8*>(&Qs[row * LDT + cv * 8]) = v;
    }
    __syncthreads();

    short4v qf[4];
    #pragma unroll
    for (int c = 0; c < 4; ++c)
        qf[c] = *reinterpret_cast<const short4v*>(&Qs[(w * 16 + lr) * LDT + c * 16 + g * 4]);

    float m_run = -1e30f, l_run = 0.f;
    f32x4 Oacc[4] = {};

    for (int kv0 = 0; kv0 < NN; kv0 += 64) {
        __syncthreads();
        // stage K tile and V^T tile
        #pragma unroll
        for (int it = 0; it < 2; ++it) {
            int idx = it * 256 + tid;
            int row = idx >> 3, cv = idx & 7;
            ushort8 kv = *reinterpret_cast<const ushort8*>(&Kb[(size_t)(b * NN + kv0 + row) * DM + h * 64 + cv * 8]);
            *reinterpret_cast<ushort8*>(&Ks[row * LDT + cv * 8]) = kv;
            ushort8 vv = *reinterpret_cast<const ushort8*>(&Vb[(size_t)(b * NN + kv0 + row) * DM + h * 64 + cv * 8]);
            #pragma unroll
            for (int j = 0; j < 8; ++j) Vts[(cv * 8 + j) * LDT + row] = vv[j];
        }
        if (tid < 64) maskS[tid] = mask[b * NN + kv0 + tid];
        __syncthreads();

        // T = K . Q^T  -> lane: q-row = lr, kj = mi*16 + 4g + i
        f32x4 facc[4];
        #pragma unroll
        for (int mi = 0; mi < 4; ++mi) {
            f32x4 t = {0.f, 0.f, 0.f, 0.f};
            #pragma unroll
            for (int c = 0; c < 4; ++c) {
                short4v kf = *reinterpret_cast<const short4v*>(&Ks[(mi * 16 + lr) * LDT + c * 16 + g * 4]);
                t = __builtin_amdgcn_mfma_f32_16x16x16bf16_1k(kf, qf[c], t, 0, 0, 0);
            }
            facc[mi] = t;
        }

        // masked online softmax (per q-row = lr, reduce over g-groups)
        float p[4][4];
        float tmax = -1e30f;
        #pragma unroll
        for (int mi = 0; mi < 4; ++mi)
            #pragma unroll
            for (int i = 0; i < 4; ++i) {
                int kj = mi * 16 + 4 * g + i;
                float s = (maskS[kj] == 0) ? -1e30f : facc[mi][i] * 0.125f;
                p[mi][i] = s;
                tmax = fmaxf(tmax, s);
            }
        tmax = fmaxf(tmax, __shfl_xor(tmax, 16));
        tmax = fmaxf(tmax, __shfl_xor(tmax, 32));
        float m_new = fmaxf(m_run, tmax);
        float alpha = __expf(m_run - m_new);
        float psum = 0.f;
        #pragma unroll
        for (int mi = 0; mi < 4; ++mi)
            #pragma unroll
            for (int i = 0; i < 4; ++i) {
                float pv = (p[mi][i] <= -1e29f) ? 0.f : __expf(p[mi][i] - m_new);
                p[mi][i] = pv;
                psum += pv;
            }
        psum += __shfl_xor(psum, 16);
        psum += __shfl_xor(psum, 32);
        l_run = l_run * alpha + psum;
        m_run = m_new;

        // rescale O (alpha per O-row 4g+i comes from lane (4g+i))
        #pragma unroll
        for (int i = 0; i < 4; ++i) {
            float ai = __shfl(alpha, 4 * g + i);
            #pragma unroll
            for (int nt = 0; nt < 4; ++nt) Oacc[nt][i] *= ai;
        }

        // PV: A = P (in-register), B = V^T fragments from LDS
        #pragma unroll
        for (int c = 0; c < 4; ++c) {
            short4v pa;
            pa[0] = (short)f2bf(p[c][0]); pa[1] = (short)f2bf(p[c][1]);
            pa[2] = (short)f2bf(p[c][2]); pa[3] = (short)f2bf(p[c][3]);
            #pragma unroll
            for (int nt = 0; nt < 4; ++nt) {
                short4v vf = *reinterpret_cast<const short4v*>(&Vts[(nt * 16 + lr) * LDT + c * 16 + g * 4]);
                Oacc[nt] = __builtin_amdgcn_mfma_f32_16x16x16bf16_1k(pa, vf, Oacc[nt], 0, 0, 0);
            }
        }
    }

    // epilogue: /l_run, *gate, store bf16
    float gv = gate[b * HH + h];
    #pragma unroll
    for (int i = 0; i < 4; ++i) {
        float li = __shfl(l_run, 4 * g + i);
        float sc = gv / li;
        int rowq = q0 + w * 16 + 4 * g + i;
        #pragma unroll
        for (int nt = 0; nt < 4; ++nt)
            attb[(size_t)(b * NN + rowq) * DM + h * 64 + nt * 16 + lr] = f2bf(Oacc[nt][i] * sc);
    }
}

// ---------------------------------------------------------------------------
extern "C" void kernel_launch(void* const* d_in, const int* in_sizes, int n_in,
                              void* d_out, int out_size, void* d_ws, size_t ws_size,
                              hipStream_t stream)
{
    const float* x    = (const float*)d_in[0];
    const int*   mask = (const int*)  d_in[1];
    const float* q    = (const float*)d_in[2];
    const float* Wq   = (const float*)d_in[3];
    const float* bq   = (const float*)d_in[4];
    const float* Wk   = (const float*)d_in[5];
    const float* bk   = (const float*)d_in[6];
    const float* Wv   = (const float*)d_in[7];
    const float* bv   = (const float*)d_in[8];
    const float* Wo   = (const float*)d_in[9];
    const float* bo   = (const float*)d_in[10];
    // d_in[11] uncertainty_bias: provably a no-op (added only to -inf logits)
    const float* Wqh  = (const float*)d_in[12];
    const float* bqh  = (const float*)d_in[13];
    float* out = (float*)d_out;

    unsigned short* xb  = (unsigned short*)d_ws;
    unsigned short* wqb = xb  + (size_t)MTOT * DM;
    unsigned short* wkb = wqb + (size_t)DM * DM;
    unsigned short* wvb = wkb + (size_t)DM * DM;
    unsigned short* wob = wvb + (size_t)DM * DM;
    unsigned short* Qb  = wob + (size_t)DM * DM;
    unsigned short* Kb  = Qb  + (size_t)MTOT * DM;
    unsigned short* Vb  = Kb  + (size_t)MTOT * DM;
    unsigned short* attb= Vb  + (size_t)MTOT * DM;
    float* gateb = (float*)(attb + (size_t)MTOT * DM);

    // 1) fp32 -> bf16 for x + 4 weight matrices
    convert_all<<<dim3(1024, 5), 256, 0, stream>>>(x, Wq, Wk, Wv, Wo, xb, wqb, wkb, wvb, wob);
    // 2) gate (tiny)
    gate_kernel<<<1, 64, 0, stream>>>(q, Wqh, bqh, gateb);
    // 3) fused QKV projections (z selects W/bias/output)
    gemm_bt<unsigned short><<<dim3(DM / 128, MTOT / 128, 3), 256, 0, stream>>>(
        xb, wqb, wkb, wvb, bq, bk, bv, Qb, Kb, Vb);
    // 4) flash attention (+gate)
    attn_kernel<<<dim3(NN / 64, HH, BB), 256, 0, stream>>>(Qb, Kb, Vb, mask, gateb, attb);
    // 5) output projection -> fp32 out
    gemm_bt<float><<<dim3(DM / 128, MTOT / 128, 1), 256, 0, stream>>>(
        attb, wob, wob, wob, bo, bo, bo, out, out, out);
}

// Round 3
// 136.604 us; speedup vs baseline: 1.8847x; 1.8847x over previous
//
#include <hip/hip_runtime.h>
#include <hip/hip_bf16.h>

typedef unsigned short ushort_t;
typedef __attribute__((ext_vector_type(4))) short  short4v;
typedef __attribute__((ext_vector_type(8))) short  short8v;
typedef __attribute__((ext_vector_type(4))) float  f32x4;
typedef __attribute__((ext_vector_type(4))) float  float4v;
typedef __attribute__((ext_vector_type(8))) unsigned short ushort8;
typedef __attribute__((ext_vector_type(4))) unsigned short ushort4v;

static constexpr int BB   = 2;
static constexpr int NN   = 2048;
static constexpr int DM   = 1024;
static constexpr int HH   = 16;
static constexpr int MTOT = BB * NN;   // 4096
// 0.125 (1/sqrt(64)) * log2(e): folds softmax scale + exp2 base change into Q
static constexpr float QSCALE = 0.18033688011112042f;

__device__ __forceinline__ ushort_t f2bf(float f) {
    return __bfloat16_as_ushort(__float2bfloat16(f));
}
__device__ __forceinline__ float exp2_fast(float x) {
    float r;
    // v_exp_f32 + 1 wait state (TRANS->VALU hazard; asm body is opaque to the
    // compiler's hazard recognizer, so include the s_nop ourselves)
    asm("v_exp_f32 %0, %1\n\ts_nop 0" : "=v"(r) : "v"(x));
    return r;
}
// async global->LDS, 16B per lane; LDS dest = wave-uniform base + lane*16
__device__ __forceinline__ void async16(const ushort_t* g, ushort_t* l) {
    __builtin_amdgcn_global_load_lds(
        (const __attribute__((address_space(1))) void*)g,
        (__attribute__((address_space(3))) void*)l, 16, 0, 0);
}

// ---------------------------------------------------------------------------
// Kernel 1: fp32 -> bf16 conversion for x, Wq, Wk, Wv, Wo (blockIdx.y selects)
// ---------------------------------------------------------------------------
__global__ __launch_bounds__(256) void convert_all(
    const float* __restrict__ x,  const float* __restrict__ wq,
    const float* __restrict__ wk, const float* __restrict__ wv,
    const float* __restrict__ wo,
    ushort_t* __restrict__ xb,  ushort_t* __restrict__ wqb,
    ushort_t* __restrict__ wkb, ushort_t* __restrict__ wvb,
    ushort_t* __restrict__ wob)
{
    const float* src; ushort_t* dst; int n;
    switch (blockIdx.y) {
        case 0: src = x;  dst = xb;  n = MTOT * DM; break;
        case 1: src = wq; dst = wqb; n = DM * DM;   break;
        case 2: src = wk; dst = wkb; n = DM * DM;   break;
        case 3: src = wv; dst = wvb; n = DM * DM;   break;
        default: src = wo; dst = wob; n = DM * DM;  break;
    }
    int nv = n >> 2;
    int stride = gridDim.x * blockDim.x;
    for (int i = blockIdx.x * blockDim.x + threadIdx.x; i < nv; i += stride) {
        float4v v = reinterpret_cast<const float4v*>(src)[i];
        ushort4v o;
        o[0] = f2bf(v[0]); o[1] = f2bf(v[1]); o[2] = f2bf(v[2]); o[3] = f2bf(v[3]);
        reinterpret_cast<ushort4v*>(dst)[i] = o;
    }
}

// ---------------------------------------------------------------------------
// Kernel 2: gate[b,h] = sigmoid(q[b,:] . Wqh[h,:] + bqh[h])   (tiny)
// ---------------------------------------------------------------------------
__global__ void gate_kernel(const float* __restrict__ q,
                            const float* __restrict__ Wqh,
                            const float* __restrict__ bqh,
                            float* __restrict__ gate)
{
    int t = threadIdx.x;
    if (t < BB * HH) {
        int b = t >> 4, h = t & 15;
        float s = bqh[h];
        for (int d = 0; d < 64; ++d) s += q[b * 64 + d] * Wqh[h * 64 + d];
        gate[t] = 1.f / (1.f + __expf(-s));
    }
}

// ---------------------------------------------------------------------------
// Kernel 3: GEMM  C[m,n] = (sum_k A[m,k] * W[n,k] + bias[n]) * scale
//   m97-style: BMx128 tile, BK=32, global_load_lds(16B), 16x16x32 MFMA.
//   LDS is linear; bank-spread comes from pre-swizzling the GLOBAL source
//   column-block and un-swizzling on the LDS read (both-sides, rule #21).
//   QKV mode (template): z=0 -> Q (scaled by QSCALE), z=1 -> K, z=2 -> V
//   written TRANSPOSED to Vt[colg][m] with packed 8B stores.
// ---------------------------------------------------------------------------
template <typename OUT, int MI, bool QKV>
__global__ __launch_bounds__(256) void gemm_bt(
    const ushort_t* __restrict__ A,
    const ushort_t* __restrict__ W0, const ushort_t* __restrict__ W1,
    const ushort_t* __restrict__ W2,
    const float* __restrict__ b0, const float* __restrict__ b1,
    const float* __restrict__ b2,
    OUT* __restrict__ C0, OUT* __restrict__ C1, OUT* __restrict__ C2,
    ushort_t* __restrict__ VtOut)
{
    constexpr int BM = MI * 32, BK = 32, K = DM, Nd = DM;
    constexpr int nA = BM * BK / 512;     // 512-elem (1KB) chunks
    constexpr int nW = 128 * BK / 512;    // = 8

    const int z = blockIdx.z;
    const ushort_t* W = (z == 0) ? W0 : (z == 1) ? W1 : W2;
    const float* bias = (z == 0) ? b0 : (z == 1) ? b1 : b2;

    __shared__ ushort_t As[BM * BK];
    __shared__ ushort_t Ws[128 * BK];

    const int tid  = threadIdx.x;
    const int lane = tid & 63;
    const int w    = tid >> 6;
    const int lr   = lane & 15;
    const int g    = lane >> 4;
    const int wm   = w >> 1, wn = w & 1;
    const int bm   = blockIdx.y * BM, bn = blockIdx.x * 128;

    // staging lane constants: row-in-chunk = lane>>2, swizzled col-block
    const int rowL = lane >> 2;                          // 0..15
    const int cb4  = ((lane & 3) ^ ((lane >> 3) & 3)) * 8;

    // fragment-read swizzle: un-XOR with (row>>1)&3 == (lr>>1)&3
    const int gx = (g ^ ((lr >> 1) & 3)) * 8;

    f32x4 acc[MI][4] = {};

    for (int k0 = 0; k0 < K; k0 += BK) {
        __syncthreads();
        #pragma unroll
        for (int ch = w; ch < nA; ch += 4)
            async16(&A[(size_t)(bm + ch * 16 + rowL) * K + k0 + cb4], &As[ch * 512]);
        #pragma unroll
        for (int ch = w; ch < nW; ch += 4)
            async16(&W[(size_t)(bn + ch * 16 + rowL) * K + k0 + cb4], &Ws[ch * 512]);
        __syncthreads();   // compiler drains vmcnt before barrier -> data ready

        short8v af[MI], bf[4];
        #pragma unroll
        for (int mi = 0; mi < MI; ++mi)
            af[mi] = *reinterpret_cast<const short8v*>(&As[(wm * (MI * 16) + mi * 16 + lr) * BK + gx]);
        #pragma unroll
        for (int ni = 0; ni < 4; ++ni)
            bf[ni] = *reinterpret_cast<const short8v*>(&Ws[(wn * 64 + ni * 16 + lr) * BK + gx]);
        #pragma unroll
        for (int mi = 0; mi < MI; ++mi)
            #pragma unroll
            for (int ni = 0; ni < 4; ++ni)
                acc[mi][ni] = __builtin_amdgcn_mfma_f32_16x16x32_bf16(af[mi], bf[ni], acc[mi][ni], 0, 0, 0);
    }

    const float scale = (QKV && z == 0) ? QSCALE : 1.f;
    if (QKV && z == 2) {
        // V: write transposed Vt[colg][m], 4 consecutive m per lane -> 8B store
        #pragma unroll
        for (int mi = 0; mi < MI; ++mi) {
            #pragma unroll
            for (int ni = 0; ni < 4; ++ni) {
                int colg = bn + wn * 64 + ni * 16 + lr;
                float bv = bias[colg];
                ushort4v pk;
                #pragma unroll
                for (int i = 0; i < 4; ++i) pk[i] = f2bf(acc[mi][ni][i] + bv);
                int rowb = bm + wm * (MI * 16) + mi * 16 + 4 * g;
                *reinterpret_cast<ushort4v*>(&VtOut[(size_t)colg * MTOT + rowb]) = pk;
            }
        }
    } else {
        OUT* C = (z == 0) ? C0 : (z == 1) ? C1 : C2;
        #pragma unroll
        for (int mi = 0; mi < MI; ++mi) {
            #pragma unroll
            for (int ni = 0; ni < 4; ++ni) {
                int colg = bn + wn * 64 + ni * 16 + lr;
                float bv = bias[colg];
                #pragma unroll
                for (int i = 0; i < 4; ++i) {
                    int rowg = bm + wm * (MI * 16) + mi * 16 + 4 * g + i;
                    float v = (acc[mi][ni][i] + bv) * scale;
                    if constexpr (sizeof(OUT) == 2) C[(size_t)rowg * Nd + colg] = (OUT)f2bf(v);
                    else                            C[(size_t)rowg * Nd + colg] = (OUT)v;
                }
            }
        }
    }
}

// ---------------------------------------------------------------------------
// Kernel 4: flash attention per (b, h). Q-tile 64, K-tile 64, 4 waves.
//   Swapped QK^T (16x16x32): lane owns q-row lr, kj = mi*16+4g+i -> P feeds
//   PV (16x16x16) directly. K and V^T staged via global_load_lds with
//   XOR-swizzled source columns; V^T comes pre-transposed from the QKV GEMM.
//   exp2-domain online softmax, additive mask bias, defer-max (THR=8 log2).
// ---------------------------------------------------------------------------
__global__ __launch_bounds__(256) void attn_kernel(
    const ushort_t* __restrict__ Qb, const ushort_t* __restrict__ Kb,
    const ushort_t* __restrict__ Vt, const int* __restrict__ mask,
    const float* __restrict__ gate, ushort_t* __restrict__ attb)
{
    __shared__ ushort_t Qs[64 * 64];
    __shared__ ushort_t Ks[64 * 64];
    __shared__ ushort_t Vts[64 * 64];   // [d][kj], swizzled col-blocks
    __shared__ float    mAdd[64];       // 0 or -1e30 per kj

    const int tid  = threadIdx.x;
    const int lane = tid & 63;
    const int w    = tid >> 6;
    const int lr   = lane & 15;
    const int g    = lane >> 4;
    const int b    = blockIdx.z, h = blockIdx.y;
    const int q0   = blockIdx.x * 64;

    // staging constants: 8 rows x 8 col-blocks per 512-elem chunk
    const int rowL  = lane >> 3;                       // 0..7
    const int cbOff = (((lane & 7) ^ rowL) & 7) * 8;   // swizzled col (elems)
    const int sA    = lr & 7;                          // read-side un-swizzle

    // stage Q tile (8 chunks, 2 per wave)
    #pragma unroll
    for (int r = 0; r < 2; ++r) {
        int ch = w * 2 + r, row = ch * 8 + rowL;
        async16(&Qb[(size_t)(b * NN + q0 + row) * DM + h * 64 + cbOff], &Qs[ch * 512]);
    }
    __syncthreads();

    short8v qf8[2];
    #pragma unroll
    for (int c = 0; c < 2; ++c)
        qf8[c] = *reinterpret_cast<const short8v*>(&Qs[(w * 16 + lr) * 64 + (((c * 4 + g) ^ sA) * 8)]);

    // hoisted V^T fragment column offsets (b64 reads, 2 per 16B slot)
    int vcol[4];
    #pragma unroll
    for (int c = 0; c < 4; ++c)
        vcol[c] = (((c * 2 + (g >> 1)) ^ sA) * 8) + (g & 1) * 4;

    const ushort_t* Kgp = &Kb[(size_t)(b * NN) * DM + h * 64 + cbOff];
    const ushort_t* Vgp = &Vt[(size_t)(h * 64) * MTOT + b * NN + cbOff];

    float m_run = -3e38f, l_run = 0.f;
    f32x4 Oacc[4] = {};

    for (int kv0 = 0; kv0 < NN; kv0 += 64) {
        __syncthreads();
        #pragma unroll
        for (int r = 0; r < 2; ++r) {
            int ch = w * 2 + r, row = ch * 8 + rowL;
            async16(Kgp + (size_t)(kv0 + row) * DM, &Ks[ch * 512]);
            async16(Vgp + (size_t)row * MTOT + kv0, &Vts[ch * 512]);
        }
        if (tid < 64) mAdd[tid] = mask[b * NN + kv0 + tid] ? 0.f : -1e30f;
        __syncthreads();

        // QK^T (swapped): facc[mi][i] = S[kj = mi*16+4g+i][q = lr] (log2 dom.)
        f32x4 facc[4];
        #pragma unroll
        for (int mi = 0; mi < 4; ++mi) {
            f32x4 t = {0.f, 0.f, 0.f, 0.f};
            #pragma unroll
            for (int c = 0; c < 2; ++c) {
                short8v kf = *reinterpret_cast<const short8v*>(
                    &Ks[(mi * 16 + lr) * 64 + (((c * 4 + g) ^ sA) * 8)]);
                t = __builtin_amdgcn_mfma_f32_16x16x32_bf16(kf, qf8[c], t, 0, 0, 0);
            }
            facc[mi] = t;
        }

        // mask bias + per-q-row max
        float pmax = -3e38f;
        #pragma unroll
        for (int mi = 0; mi < 4; ++mi) {
            f32x4 ma = *reinterpret_cast<const f32x4*>(&mAdd[mi * 16 + 4 * g]);
            #pragma unroll
            for (int i = 0; i < 4; ++i) {
                float s = facc[mi][i] + ma[i];
                facc[mi][i] = s;
                pmax = fmaxf(pmax, s);
            }
        }
        pmax = fmaxf(pmax, __shfl_xor(pmax, 16));
        pmax = fmaxf(pmax, __shfl_xor(pmax, 32));

        // defer-max: only rescale when the running max grew by > 8 (log2)
        if (!__all(pmax <= m_run + 8.f)) {
            float m_new = fmaxf(m_run, pmax);
            float alpha = exp2_fast(m_run - m_new);
            l_run *= alpha;
            #pragma unroll
            for (int i = 0; i < 4; ++i) {
                float ai = __shfl(alpha, 4 * g + i);
                #pragma unroll
                for (int nt = 0; nt < 4; ++nt) Oacc[nt][i] *= ai;
            }
            m_run = m_new;
        }

        // P = exp2(S - m); masked entries underflow to exactly 0
        float psum = 0.f;
        short4v pa[4];
        #pragma unroll
        for (int mi = 0; mi < 4; ++mi) {
            #pragma unroll
            for (int i = 0; i < 4; ++i) {
                float pv = exp2_fast(facc[mi][i] - m_run);
                psum += pv;
                pa[mi][i] = (short)f2bf(pv);
            }
        }
        psum += __shfl_xor(psum, 16);
        psum += __shfl_xor(psum, 32);
        l_run += psum;

        // PV: A = P (in-register, layout-exact), B = V^T fragments
        #pragma unroll
        for (int c = 0; c < 4; ++c) {
            #pragma unroll
            for (int nt = 0; nt < 4; ++nt) {
                short4v vf = *reinterpret_cast<const short4v*>(&Vts[(nt * 16 + lr) * 64 + vcol[c]]);
                Oacc[nt] = __builtin_amdgcn_mfma_f32_16x16x16bf16_1k(pa[c], vf, Oacc[nt], 0, 0, 0);
            }
        }
    }

    // epilogue: /l, *gate, bf16 store
    float gv = gate[b * HH + h];
    #pragma unroll
    for (int i = 0; i < 4; ++i) {
        float li = __shfl(l_run, 4 * g + i);
        float sc = gv / li;
        int rowq = q0 + w * 16 + 4 * g + i;
        #pragma unroll
        for (int nt = 0; nt < 4; ++nt)
            attb[(size_t)(b * NN + rowq) * DM + h * 64 + nt * 16 + lr] = f2bf(Oacc[nt][i] * sc);
    }
}

// ---------------------------------------------------------------------------
extern "C" void kernel_launch(void* const* d_in, const int* in_sizes, int n_in,
                              void* d_out, int out_size, void* d_ws, size_t ws_size,
                              hipStream_t stream)
{
    const float* x    = (const float*)d_in[0];
    const int*   mask = (const int*)  d_in[1];
    const float* q    = (const float*)d_in[2];
    const float* Wq   = (const float*)d_in[3];
    const float* bq   = (const float*)d_in[4];
    const float* Wk   = (const float*)d_in[5];
    const float* bk   = (const float*)d_in[6];
    const float* Wv   = (const float*)d_in[7];
    const float* bv   = (const float*)d_in[8];
    const float* Wo   = (const float*)d_in[9];
    const float* bo   = (const float*)d_in[10];
    // d_in[11] uncertainty_bias: provably a no-op (added only to -inf logits)
    const float* Wqh  = (const float*)d_in[12];
    const float* bqh  = (const float*)d_in[13];
    float* out = (float*)d_out;

    ushort_t* xb  = (ushort_t*)d_ws;
    ushort_t* wqb = xb  + (size_t)MTOT * DM;
    ushort_t* wkb = wqb + (size_t)DM * DM;
    ushort_t* wvb = wkb + (size_t)DM * DM;
    ushort_t* wob = wvb + (size_t)DM * DM;
    ushort_t* Qb  = wob + (size_t)DM * DM;
    ushort_t* Kb  = Qb  + (size_t)MTOT * DM;
    ushort_t* Vtb = Kb  + (size_t)MTOT * DM;   // [1024][4096] transposed V
    ushort_t* attb= Vtb + (size_t)MTOT * DM;
    float* gateb = (float*)(attb + (size_t)MTOT * DM);

    convert_all<<<dim3(1024, 5), 256, 0, stream>>>(x, Wq, Wk, Wv, Wo, xb, wqb, wkb, wvb, wob);
    gate_kernel<<<1, 64, 0, stream>>>(q, Wqh, bqh, gateb);
    // fused QKV projections; V is written transposed into Vtb
    gemm_bt<ushort_t, 4, true><<<dim3(DM / 128, MTOT / 128, 3), 256, 0, stream>>>(
        xb, wqb, wkb, wvb, bq, bk, bv, Qb, Kb, (ushort_t*)nullptr, Vtb);
    attn_kernel<<<dim3(NN / 64, HH, BB), 256, 0, stream>>>(Qb, Kb, Vtb, mask, gateb, attb);
    // output projection (BM=64 -> 512 blocks for occupancy)
    gemm_bt<float, 2, false><<<dim3(DM / 128, MTOT / 64, 1), 256, 0, stream>>>(
        attb, wob, wob, wob, bo, bo, bo, out, out, out, (ushort_t*)nullptr);
}